// Round 6
// baseline (226.288 us; speedup 1.0000x reference)
//
#include <hip/hip_runtime.h>

// PositionalEncoding: out[b,s,i] = x[b,s,i] + pe[s,i]
//   pe[s,i] = sin(s / 10000^((i/2)/D)) if i even, cos(...) if i odd
// B=8, S=4096, D=1024, fp32.
//
// R9: grid-stride structure (copy-bench shape), trig unchanged from R6.
// Evidence trail:
//  - Cache policy space exhausted: nt load > temporal load (216.3 vs
//    220.2); nt store == plain store (216.3 vs 216.7). 512MB poison fill
//    sweeps L3 every iter -> all 268 MB is mandatory HBM traffic.
//  - Kernel est. ~68 us = 3.9 TB/s vs 6.29 TB/s measured mixed-copy
//    ceiling (m13) => 1.6x structural gap, not a roofline.
//  - Untested axis: dispatch shape. Was 32768 one-shot blocks, one
//    load->wait->store round trip per thread. Now: 2048 persistent
//    blocks x 256 thr, 16 float4/thread grid-stride, unroll 4 -> four
//    independent 1KB loads in flight per wave, store(k) overlaps
//    load(k+1), dispatch ramp amortized (Guideline 11 / m13 shape).
// pe math: revolutions-domain v_sin/v_cos (branch-free), absmax 0.03125.

#define PE_B 8
#define PE_S 4096
#define PE_D 1024
#define ROW4 (PE_S * PE_D / 4)          // float4s per batch = 1,048,576
#define N4   (PE_B * ROW4)              // total float4s = 8,388,608
#define GSB  2048                       // blocks
#define TPB  256                        // threads/block
#define GSTRIDE (GSB * TPB)             // 524,288 float4s per sweep
#define ITERS (N4 / GSTRIDE)            // 16

typedef float v4f __attribute__((ext_vector_type(4)));

__global__ __launch_bounds__(256) void pe_fused_gs(
    const float* __restrict__ x, float* __restrict__ out) {
    const int tid0 = blockIdx.x * TPB + threadIdx.x;

#pragma unroll 4
    for (int it = 0; it < ITERS; ++it) {
        const int idx = tid0 + it * GSTRIDE;               // 0 .. N4-1
        const int r   = idx & (ROW4 - 1);
        const int i   = (r & (PE_D / 4 - 1)) * 4;          // elem index in row
        const int s   = r >> 8;                            // D/4 = 256

        const v4f v = __builtin_nontemporal_load(
            (const v4f*)(x + (size_t)idx * 4));

        // rev = pos * 10000^(-k/D) / (2*pi)   (angle in revolutions)
        const float pos = (float)s;
        const float c   = -0.012976281620653759f;   // -log2(10000)/1024
        const float L   = -2.6514961294723187f;     // -log2(2*pi)
        const float k0  = (float)(i >> 1);
        const float w0  = __builtin_amdgcn_exp2f(fmaf(k0,        c, L));
        const float w1  = __builtin_amdgcn_exp2f(fmaf(k0 + 1.0f, c, L));
        // range-reduce to [-0.5,0.5] revolutions; fma = single-rounding fract
        const float f0  = fmaf(pos, w0, -rintf(pos * w0));
        const float f1  = fmaf(pos, w1, -rintf(pos * w1));
        const v4f pe = { __builtin_amdgcn_sinf(f0), __builtin_amdgcn_cosf(f0),
                         __builtin_amdgcn_sinf(f1), __builtin_amdgcn_cosf(f1) };

        __builtin_nontemporal_store(v + pe, (v4f*)(out + (size_t)idx * 4));
    }
}

extern "C" void kernel_launch(void* const* d_in, const int* in_sizes, int n_in,
                              void* d_out, int out_size, void* d_ws, size_t ws_size,
                              hipStream_t stream) {
    const float* x = (const float*)d_in[0];
    float* out = (float*)d_out;
    (void)d_ws; (void)ws_size;
    pe_fused_gs<<<GSB, TPB, 0, stream>>>(x, out);
}

// Round 7
// 215.158 us; speedup vs baseline: 1.0517x; 1.0517x over previous
//
#include <hip/hip_runtime.h>

// PositionalEncoding: out[b,s,i] = x[b,s,i] + pe[s,i]
//   pe[s,i] = sin(s / 10000^((i/2)/D)) if i even, cos(...) if i odd
// B=8, S=4096, D=1024, fp32.
//
// R10: one-shot blocks with 4-way block-local ILP (the untested axis).
// Evidence trail:
//  - nt load > temporal (216.3 vs 220.2); nt store == plain (216.3/216.7).
//  - 16MB-stride batch-amortize: 2.2 TB/s (TLB). 8MB-stride grid-stride:
//    regressed (226.3). Long strides are dead.
//  - Both one-shot 1-float4/thread kernels sit at 3.7-3.9 TB/s vs
//    6.29 TB/s mixed-copy ceiling; the only structural difference left
//    vs the copy bench is memory-level parallelism per thread.
// Structure: block owns 16 KB contiguous (4 chunks x 256 float4s);
// thread t handles chunk offsets {0,1,2,3}*256 -- per-instruction lane
// contiguity kept, strides only 4 KB, 4 independent loads in flight,
// store(k) overlaps trig(k+1). Chunk loop keeps i invariant -> the two
// exp2 freqs hoist; s increments by 1/chunk. 1024 | ROW4 so no block
// crosses a row/batch boundary.
// pe math: revolutions-domain v_sin/v_cos (branch-free), absmax 0.03125.

#define PE_B 8
#define PE_S 4096
#define PE_D 1024
#define ROW4 (PE_S * PE_D / 4)          // float4s per batch = 1,048,576
#define N4   (PE_B * ROW4)              // total float4s = 8,388,608
#define CHUNKS 4
#define TPB  256

typedef float v4f __attribute__((ext_vector_type(4)));

__global__ __launch_bounds__(256) void pe_fused_ilp4(
    const float* __restrict__ x, float* __restrict__ out) {
    const int l = threadIdx.x;
    const size_t base = (size_t)blockIdx.x * (CHUNKS * TPB) + l; // float4 idx, chunk 0
    const int r0 = (int)(base & (ROW4 - 1));
    const int i  = l * 4;                     // elem index in row (chunk-invariant)
    const int s0 = r0 >> 8;                   // seq pos of chunk 0

    // --- 4 independent loads in flight ---
    v4f v0 = __builtin_nontemporal_load((const v4f*)(x + (base           ) * 4));
    v4f v1 = __builtin_nontemporal_load((const v4f*)(x + (base + 1 * TPB ) * 4));
    v4f v2 = __builtin_nontemporal_load((const v4f*)(x + (base + 2 * TPB ) * 4));
    v4f v3 = __builtin_nontemporal_load((const v4f*)(x + (base + 3 * TPB ) * 4));

    // --- chunk-invariant frequencies (hoisted) ---
    const float c  = -0.012976281620653759f;   // -log2(10000)/1024
    const float L  = -2.6514961294723187f;     // -log2(2*pi)
    const float k0 = (float)(i >> 1);
    const float w0 = __builtin_amdgcn_exp2f(fmaf(k0,        c, L));
    const float w1 = __builtin_amdgcn_exp2f(fmaf(k0 + 1.0f, c, L));

    v4f vv[4] = {v0, v1, v2, v3};
#pragma unroll
    for (int k = 0; k < CHUNKS; ++k) {
        const float pos = (float)(s0 + k);
        const float f0  = fmaf(pos, w0, -rintf(pos * w0));
        const float f1  = fmaf(pos, w1, -rintf(pos * w1));
        const v4f pe = { __builtin_amdgcn_sinf(f0), __builtin_amdgcn_cosf(f0),
                         __builtin_amdgcn_sinf(f1), __builtin_amdgcn_cosf(f1) };
        __builtin_nontemporal_store(vv[k] + pe,
                                    (v4f*)(out + (base + (size_t)k * TPB) * 4));
    }
}

extern "C" void kernel_launch(void* const* d_in, const int* in_sizes, int n_in,
                              void* d_out, int out_size, void* d_ws, size_t ws_size,
                              hipStream_t stream) {
    const float* x = (const float*)d_in[0];
    float* out = (float*)d_out;
    (void)d_ws; (void)ws_size;
    pe_fused_ilp4<<<N4 / (CHUNKS * TPB), TPB, 0, stream>>>(x, out);
}